// Round 1
// baseline (2916.624 us; speedup 1.0000x reference)
//
#include <hip/hip_runtime.h>

#define N_NODES 50000
#define N_EDGES 800000
// D_S=64, D_R=16, D_E=64, D_X=16, D_P=64, NUM_CLASSES=10
// W_r: [144,64] row-major; W_o: [144,64]; W_s: [64,10]

// FMA of a broadcast scalar (per-lane VGPR) against a wave-uniform W row.
// W row pointer is uniform across lanes -> compiler emits s_load + v_fmac
// with SGPR operand: 1 VALU instruction per FMA.
#define ACC_FMA64(bval, wrow)                          \
    do {                                               \
        const float* __w = (wrow);                     \
        _Pragma("unroll")                              \
        for (int j = 0; j < 64; ++j)                   \
            acc[j] = fmaf((bval), __w[j], acc[j]);     \
    } while (0)

__global__ __launch_bounds__(256) void in_edge_kernel(
    const float* __restrict__ O,
    const float* __restrict__ R_a,
    const int* __restrict__ senders,
    const int* __restrict__ receivers,
    const float* __restrict__ W_r,
    const float* __restrict__ b_r,
    float* __restrict__ E_hat)
{
    const int e = blockIdx.x * blockDim.x + threadIdx.x;
    if (e >= N_EDGES) return;
    const int s = senders[e];
    const int r = receivers[e];

    float acc[64];
#pragma unroll
    for (int j = 0; j < 64; ++j) acc[j] = b_r[j];

    // ---- sender part: k = 0..63, W_r rows 0..63 ----
    {
        const float4* Ov = reinterpret_cast<const float4*>(O + (size_t)s * 64);
#pragma unroll 2
        for (int kc = 0; kc < 16; ++kc) {
            const float4 b4 = Ov[kc];
            const int k0 = kc * 4;
            ACC_FMA64(b4.x, W_r + (size_t)(k0 + 0) * 64);
            ACC_FMA64(b4.y, W_r + (size_t)(k0 + 1) * 64);
            ACC_FMA64(b4.z, W_r + (size_t)(k0 + 2) * 64);
            ACC_FMA64(b4.w, W_r + (size_t)(k0 + 3) * 64);
        }
    }
    // ---- receiver part: k = 64..127, W_r rows 64..127 ----
    {
        const float4* Ov = reinterpret_cast<const float4*>(O + (size_t)r * 64);
#pragma unroll 2
        for (int kc = 0; kc < 16; ++kc) {
            const float4 b4 = Ov[kc];
            const int k0 = 64 + kc * 4;
            ACC_FMA64(b4.x, W_r + (size_t)(k0 + 0) * 64);
            ACC_FMA64(b4.y, W_r + (size_t)(k0 + 1) * 64);
            ACC_FMA64(b4.z, W_r + (size_t)(k0 + 2) * 64);
            ACC_FMA64(b4.w, W_r + (size_t)(k0 + 3) * 64);
        }
    }
    // ---- relation-attr part: k = 128..143, W_r rows 128..143 ----
    {
        const float4* Rv = reinterpret_cast<const float4*>(R_a + (size_t)e * 16);
#pragma unroll
        for (int kc = 0; kc < 4; ++kc) {
            const float4 b4 = Rv[kc];
            const int k0 = 128 + kc * 4;
            ACC_FMA64(b4.x, W_r + (size_t)(k0 + 0) * 64);
            ACC_FMA64(b4.y, W_r + (size_t)(k0 + 1) * 64);
            ACC_FMA64(b4.z, W_r + (size_t)(k0 + 2) * 64);
            ACC_FMA64(b4.w, W_r + (size_t)(k0 + 3) * 64);
        }
    }

    // ---- scatter-add onto receiver node ----
    float* dst = E_hat + (size_t)r * 64;
#pragma unroll
    for (int j = 0; j < 64; ++j) atomicAdd(dst + j, acc[j]);
}

__global__ __launch_bounds__(256) void in_node_kernel(
    const float* __restrict__ O,
    const float* __restrict__ X,
    const float* __restrict__ E_hat,
    const float* __restrict__ W_o,
    const float* __restrict__ b_o,
    const float* __restrict__ W_s,
    const float* __restrict__ b_s,
    float* __restrict__ out)
{
    const int n = blockIdx.x * blockDim.x + threadIdx.x;
    if (n >= N_NODES) return;

    float acc[64];
#pragma unroll
    for (int j = 0; j < 64; ++j) acc[j] = b_o[j];

    // ---- O part: k = 0..63 ----
    {
        const float4* Ov = reinterpret_cast<const float4*>(O + (size_t)n * 64);
#pragma unroll 2
        for (int kc = 0; kc < 16; ++kc) {
            const float4 b4 = Ov[kc];
            const int k0 = kc * 4;
            ACC_FMA64(b4.x, W_o + (size_t)(k0 + 0) * 64);
            ACC_FMA64(b4.y, W_o + (size_t)(k0 + 1) * 64);
            ACC_FMA64(b4.z, W_o + (size_t)(k0 + 2) * 64);
            ACC_FMA64(b4.w, W_o + (size_t)(k0 + 3) * 64);
        }
    }
    // ---- X part: k = 64..79 ----
    {
        const float4* Xv = reinterpret_cast<const float4*>(X + (size_t)n * 16);
#pragma unroll
        for (int kc = 0; kc < 4; ++kc) {
            const float4 b4 = Xv[kc];
            const int k0 = 64 + kc * 4;
            ACC_FMA64(b4.x, W_o + (size_t)(k0 + 0) * 64);
            ACC_FMA64(b4.y, W_o + (size_t)(k0 + 1) * 64);
            ACC_FMA64(b4.z, W_o + (size_t)(k0 + 2) * 64);
            ACC_FMA64(b4.w, W_o + (size_t)(k0 + 3) * 64);
        }
    }
    // ---- E_hat part: k = 80..143 ----
    {
        const float4* Ev = reinterpret_cast<const float4*>(E_hat + (size_t)n * 64);
#pragma unroll 2
        for (int kc = 0; kc < 16; ++kc) {
            const float4 b4 = Ev[kc];
            const int k0 = 80 + kc * 4;
            ACC_FMA64(b4.x, W_o + (size_t)(k0 + 0) * 64);
            ACC_FMA64(b4.y, W_o + (size_t)(k0 + 1) * 64);
            ACC_FMA64(b4.z, W_o + (size_t)(k0 + 2) * 64);
            ACC_FMA64(b4.w, W_o + (size_t)(k0 + 3) * 64);
        }
    }

    // ---- classifier: scores = P @ W_s + b_s ----
    float sc[10];
#pragma unroll
    for (int c = 0; c < 10; ++c) sc[c] = b_s[c];
#pragma unroll 8
    for (int j = 0; j < 64; ++j) {
        const float* ws = W_s + (size_t)j * 10;
        const float p = acc[j];
#pragma unroll
        for (int c = 0; c < 10; ++c) sc[c] = fmaf(p, ws[c], sc[c]);
    }

    // ---- softmax over 10 classes ----
    float m = sc[0];
#pragma unroll
    for (int c = 1; c < 10; ++c) m = fmaxf(m, sc[c]);
    float sum = 0.f;
#pragma unroll
    for (int c = 0; c < 10; ++c) {
        sc[c] = expf(sc[c] - m);
        sum += sc[c];
    }
    const float inv = 1.0f / sum;
    float* o = out + (size_t)n * 10;
#pragma unroll
    for (int c = 0; c < 10; ++c) o[c] = sc[c] * inv;
}

extern "C" void kernel_launch(void* const* d_in, const int* in_sizes, int n_in,
                              void* d_out, int out_size, void* d_ws, size_t ws_size,
                              hipStream_t stream)
{
    const float* O    = (const float*)d_in[0];
    const float* X    = (const float*)d_in[1];
    const float* R_a  = (const float*)d_in[2];
    const int* senders   = (const int*)d_in[3];
    const int* receivers = (const int*)d_in[4];
    const float* W_r  = (const float*)d_in[5];
    const float* b_r  = (const float*)d_in[6];
    const float* W_o  = (const float*)d_in[7];
    const float* b_o  = (const float*)d_in[8];
    const float* W_s  = (const float*)d_in[9];
    const float* b_s  = (const float*)d_in[10];
    float* out   = (float*)d_out;
    float* E_hat = (float*)d_ws;  // N_NODES*64 f32 = 12.8 MB scratch

    // E_hat must be zeroed every call (atomics accumulate into it).
    hipMemsetAsync(E_hat, 0, (size_t)N_NODES * 64 * sizeof(float), stream);

    in_edge_kernel<<<N_EDGES / 256, 256, 0, stream>>>(
        O, R_a, senders, receivers, W_r, b_r, E_hat);

    in_node_kernel<<<(N_NODES + 255) / 256, 256, 0, stream>>>(
        O, X, E_hat, W_o, b_o, W_s, b_s, out);
}

// Round 3
// 383.627 us; speedup vs baseline: 7.6028x; 7.6028x over previous
//
#include <hip/hip_runtime.h>

#define N_NODES 50000
#define N_EDGES 800000
// D_S=64, D_R=16, D_E=64, D_X=16, D_P=64, NUM_CLASSES=10
// W_r: [144,64] row-major; W_o: [144,64]; W_s: [64,10]

// FMA of a per-lane scalar against a wave-uniform W row (64 wide).
// W row pointer is uniform -> s_load + v_fmac with SGPR operand.
#define ROW_FMA64(accv, bval, wrow)                    \
    do {                                               \
        const float* __w = (wrow);                     \
        const float __b = (bval);                      \
        _Pragma("unroll")                              \
        for (int _j = 0; _j < 64; ++_j)                \
            accv[_j] = fmaf(__b, __w[_j], accv[_j]);   \
    } while (0)

// ---------------------------------------------------------------------------
// Sort-by-receiver passes
// ---------------------------------------------------------------------------
__global__ __launch_bounds__(256) void count_rank_kernel(
    const int* __restrict__ receivers,
    int* __restrict__ count,
    int* __restrict__ rank)
{
    const int e = blockIdx.x * blockDim.x + threadIdx.x;
    if (e >= N_EDGES) return;
    const int r = receivers[e];
    rank[e] = atomicAdd(count + r, 1);
}

#define SCAN_BLOCK 1024
#define SCAN_CHUNK ((N_NODES + SCAN_BLOCK - 1) / SCAN_BLOCK)  // 49

__global__ __launch_bounds__(SCAN_BLOCK) void scan_kernel(
    const int* __restrict__ count,
    int* __restrict__ off)
{
    __shared__ int tmp[SCAN_BLOCK];
    const int t = threadIdx.x;
    const int base = t * SCAN_CHUNK;
    int s = 0;
    for (int i = 0; i < SCAN_CHUNK; ++i) {
        const int idx = base + i;
        if (idx < N_NODES) s += count[idx];
    }
    tmp[t] = s;
    __syncthreads();
    // Hillis-Steele inclusive scan over 1024 partials
    for (int d = 1; d < SCAN_BLOCK; d <<= 1) {
        int v = (t >= d) ? tmp[t - d] : 0;
        __syncthreads();
        tmp[t] += v;
        __syncthreads();
    }
    int run = tmp[t] - s;  // exclusive prefix for this thread's chunk
    for (int i = 0; i < SCAN_CHUNK; ++i) {
        const int idx = base + i;
        if (idx < N_NODES) {
            off[idx] = run;
            run += count[idx];
        }
    }
    if (t == SCAN_BLOCK - 1) off[N_NODES] = tmp[SCAN_BLOCK - 1];
}

__global__ __launch_bounds__(256) void place_kernel(
    const int* __restrict__ receivers,
    const int* __restrict__ rank,
    const int* __restrict__ off,
    int* __restrict__ perm)
{
    const int e = blockIdx.x * blockDim.x + threadIdx.x;
    if (e >= N_EDGES) return;
    const int r = receivers[e];
    perm[off[r] + rank[e]] = e;
}

// ---------------------------------------------------------------------------
// Wave-per-node gather-aggregate: S_send[n] = sum O[s_e], S_ra[n] = sum R_a[e]
// ---------------------------------------------------------------------------
__global__ __launch_bounds__(256) void agg_kernel(
    const float* __restrict__ O,
    const float* __restrict__ R_a,
    const int* __restrict__ senders,
    const int* __restrict__ perm,
    const int* __restrict__ off,
    float* __restrict__ S_send,
    float* __restrict__ S_ra,
    float* __restrict__ degf)
{
    const int lane = threadIdx.x & 63;
    const int wid = threadIdx.x >> 6;
    const int n = blockIdx.x * 4 + wid;
    if (n >= N_NODES) return;

    const int beg = off[n];
    const int end = off[n + 1];

    float s0 = 0.f, s1 = 0.f, ra0 = 0.f, ra1 = 0.f;
    int i = beg;
    for (; i + 1 < end; i += 2) {
        const int e0 = perm[i];
        const int e1 = perm[i + 1];
        const int a0 = senders[e0];
        const int a1 = senders[e1];
        s0 += O[(size_t)a0 * 64 + lane];
        s1 += O[(size_t)a1 * 64 + lane];
        if (lane < 16) {
            ra0 += R_a[(size_t)e0 * 16 + lane];
            ra1 += R_a[(size_t)e1 * 16 + lane];
        }
    }
    if (i < end) {
        const int e0 = perm[i];
        const int a0 = senders[e0];
        s0 += O[(size_t)a0 * 64 + lane];
        if (lane < 16) ra0 += R_a[(size_t)e0 * 16 + lane];
    }

    S_send[(size_t)n * 64 + lane] = s0 + s1;
    if (lane < 16) S_ra[(size_t)n * 16 + lane] = ra0 + ra1;
    if (lane == 0) degf[n] = (float)(end - beg);
}

// ---------------------------------------------------------------------------
// Fused node kernel: E_hat (registers) -> P -> classifier -> softmax
// ---------------------------------------------------------------------------
__global__ __launch_bounds__(256) void fused_node_kernel(
    const float* __restrict__ O,
    const float* __restrict__ X,
    const float* __restrict__ S_send,
    const float* __restrict__ S_ra,
    const float* __restrict__ degf,
    const float* __restrict__ W_r,
    const float* __restrict__ b_r,
    const float* __restrict__ W_o,
    const float* __restrict__ b_o,
    const float* __restrict__ W_s,
    const float* __restrict__ b_s,
    float* __restrict__ out)
{
    const int n = blockIdx.x * blockDim.x + threadIdx.x;
    if (n >= N_NODES) return;

    // ---- E_hat[n] = S_send@W_r[0:64] + deg*(O[n]@W_r[64:128] + b_r) + S_ra@W_r[128:144]
    float eh[64];
#pragma unroll
    for (int j = 0; j < 64; ++j) eh[j] = b_r[j];

    const float4* Ov = reinterpret_cast<const float4*>(O + (size_t)n * 64);
#pragma unroll 2
    for (int kc = 0; kc < 16; ++kc) {
        const float4 b4 = Ov[kc];
        const int k0 = kc * 4;
        ROW_FMA64(eh, b4.x, W_r + (size_t)(64 + k0 + 0) * 64);
        ROW_FMA64(eh, b4.y, W_r + (size_t)(64 + k0 + 1) * 64);
        ROW_FMA64(eh, b4.z, W_r + (size_t)(64 + k0 + 2) * 64);
        ROW_FMA64(eh, b4.w, W_r + (size_t)(64 + k0 + 3) * 64);
    }
    const float dg = degf[n];
#pragma unroll
    for (int j = 0; j < 64; ++j) eh[j] *= dg;

    {
        const float4* Sv = reinterpret_cast<const float4*>(S_send + (size_t)n * 64);
#pragma unroll 2
        for (int kc = 0; kc < 16; ++kc) {
            const float4 b4 = Sv[kc];
            const int k0 = kc * 4;
            ROW_FMA64(eh, b4.x, W_r + (size_t)(k0 + 0) * 64);
            ROW_FMA64(eh, b4.y, W_r + (size_t)(k0 + 1) * 64);
            ROW_FMA64(eh, b4.z, W_r + (size_t)(k0 + 2) * 64);
            ROW_FMA64(eh, b4.w, W_r + (size_t)(k0 + 3) * 64);
        }
    }
    {
        const float4* Rv = reinterpret_cast<const float4*>(S_ra + (size_t)n * 16);
#pragma unroll
        for (int kc = 0; kc < 4; ++kc) {
            const float4 b4 = Rv[kc];
            const int k0 = 128 + kc * 4;
            ROW_FMA64(eh, b4.x, W_r + (size_t)(k0 + 0) * 64);
            ROW_FMA64(eh, b4.y, W_r + (size_t)(k0 + 1) * 64);
            ROW_FMA64(eh, b4.z, W_r + (size_t)(k0 + 2) * 64);
            ROW_FMA64(eh, b4.w, W_r + (size_t)(k0 + 3) * 64);
        }
    }

    // ---- P = concat(O, X, E_hat) @ W_o + b_o
    float acc[64];
#pragma unroll
    for (int j = 0; j < 64; ++j) acc[j] = b_o[j];

#pragma unroll 2
    for (int kc = 0; kc < 16; ++kc) {
        const float4 b4 = Ov[kc];
        const int k0 = kc * 4;
        ROW_FMA64(acc, b4.x, W_o + (size_t)(k0 + 0) * 64);
        ROW_FMA64(acc, b4.y, W_o + (size_t)(k0 + 1) * 64);
        ROW_FMA64(acc, b4.z, W_o + (size_t)(k0 + 2) * 64);
        ROW_FMA64(acc, b4.w, W_o + (size_t)(k0 + 3) * 64);
    }
    {
        const float4* Xv = reinterpret_cast<const float4*>(X + (size_t)n * 16);
#pragma unroll
        for (int kc = 0; kc < 4; ++kc) {
            const float4 b4 = Xv[kc];
            const int k0 = 64 + kc * 4;
            ROW_FMA64(acc, b4.x, W_o + (size_t)(k0 + 0) * 64);
            ROW_FMA64(acc, b4.y, W_o + (size_t)(k0 + 1) * 64);
            ROW_FMA64(acc, b4.z, W_o + (size_t)(k0 + 2) * 64);
            ROW_FMA64(acc, b4.w, W_o + (size_t)(k0 + 3) * 64);
        }
    }
#pragma unroll
    for (int k = 0; k < 64; ++k) {
        ROW_FMA64(acc, eh[k], W_o + (size_t)(80 + k) * 64);
    }

    // ---- classifier: scores = P @ W_s + b_s
    float sc[10];
#pragma unroll
    for (int c = 0; c < 10; ++c) sc[c] = b_s[c];
#pragma unroll 8
    for (int j = 0; j < 64; ++j) {
        const float* ws = W_s + (size_t)j * 10;
        const float p = acc[j];
#pragma unroll
        for (int c = 0; c < 10; ++c) sc[c] = fmaf(p, ws[c], sc[c]);
    }

    // ---- softmax over 10 classes
    float m = sc[0];
#pragma unroll
    for (int c = 1; c < 10; ++c) m = fmaxf(m, sc[c]);
    float sum = 0.f;
#pragma unroll
    for (int c = 0; c < 10; ++c) {
        sc[c] = expf(sc[c] - m);
        sum += sc[c];
    }
    const float inv = 1.0f / sum;
    float* o = out + (size_t)n * 10;
#pragma unroll
    for (int c = 0; c < 10; ++c) o[c] = sc[c] * inv;
}

// ---------------------------------------------------------------------------
// Fallback path (round-0 structure) if workspace is too small
// ---------------------------------------------------------------------------
__global__ __launch_bounds__(256) void in_edge_kernel(
    const float* __restrict__ O,
    const float* __restrict__ R_a,
    const int* __restrict__ senders,
    const int* __restrict__ receivers,
    const float* __restrict__ W_r,
    const float* __restrict__ b_r,
    float* __restrict__ E_hat)
{
    const int e = blockIdx.x * blockDim.x + threadIdx.x;
    if (e >= N_EDGES) return;
    const int s = senders[e];
    const int r = receivers[e];

    float acc[64];
#pragma unroll
    for (int j = 0; j < 64; ++j) acc[j] = b_r[j];

    {
        const float4* Ov = reinterpret_cast<const float4*>(O + (size_t)s * 64);
#pragma unroll 2
        for (int kc = 0; kc < 16; ++kc) {
            const float4 b4 = Ov[kc];
            const int k0 = kc * 4;
            ROW_FMA64(acc, b4.x, W_r + (size_t)(k0 + 0) * 64);
            ROW_FMA64(acc, b4.y, W_r + (size_t)(k0 + 1) * 64);
            ROW_FMA64(acc, b4.z, W_r + (size_t)(k0 + 2) * 64);
            ROW_FMA64(acc, b4.w, W_r + (size_t)(k0 + 3) * 64);
        }
    }
    {
        const float4* Ov = reinterpret_cast<const float4*>(O + (size_t)r * 64);
#pragma unroll 2
        for (int kc = 0; kc < 16; ++kc) {
            const float4 b4 = Ov[kc];
            const int k0 = 64 + kc * 4;
            ROW_FMA64(acc, b4.x, W_r + (size_t)(k0 + 0) * 64);
            ROW_FMA64(acc, b4.y, W_r + (size_t)(k0 + 1) * 64);
            ROW_FMA64(acc, b4.z, W_r + (size_t)(k0 + 2) * 64);
            ROW_FMA64(acc, b4.w, W_r + (size_t)(k0 + 3) * 64);
        }
    }
    {
        const float4* Rv = reinterpret_cast<const float4*>(R_a + (size_t)e * 16);
#pragma unroll
        for (int kc = 0; kc < 4; ++kc) {
            const float4 b4 = Rv[kc];
            const int k0 = 128 + kc * 4;
            ROW_FMA64(acc, b4.x, W_r + (size_t)(k0 + 0) * 64);
            ROW_FMA64(acc, b4.y, W_r + (size_t)(k0 + 1) * 64);
            ROW_FMA64(acc, b4.z, W_r + (size_t)(k0 + 2) * 64);
            ROW_FMA64(acc, b4.w, W_r + (size_t)(k0 + 3) * 64);
        }
    }

    float* dst = E_hat + (size_t)r * 64;
#pragma unroll
    for (int j = 0; j < 64; ++j) atomicAdd(dst + j, acc[j]);
}

__global__ __launch_bounds__(256) void in_node_kernel(
    const float* __restrict__ O,
    const float* __restrict__ X,
    const float* __restrict__ E_hat,
    const float* __restrict__ W_o,
    const float* __restrict__ b_o,
    const float* __restrict__ W_s,
    const float* __restrict__ b_s,
    float* __restrict__ out)
{
    const int n = blockIdx.x * blockDim.x + threadIdx.x;
    if (n >= N_NODES) return;

    float acc[64];
#pragma unroll
    for (int j = 0; j < 64; ++j) acc[j] = b_o[j];

    {
        const float4* Ov = reinterpret_cast<const float4*>(O + (size_t)n * 64);
#pragma unroll 2
        for (int kc = 0; kc < 16; ++kc) {
            const float4 b4 = Ov[kc];
            const int k0 = kc * 4;
            ROW_FMA64(acc, b4.x, W_o + (size_t)(k0 + 0) * 64);
            ROW_FMA64(acc, b4.y, W_o + (size_t)(k0 + 1) * 64);
            ROW_FMA64(acc, b4.z, W_o + (size_t)(k0 + 2) * 64);
            ROW_FMA64(acc, b4.w, W_o + (size_t)(k0 + 3) * 64);
        }
    }
    {
        const float4* Xv = reinterpret_cast<const float4*>(X + (size_t)n * 16);
#pragma unroll
        for (int kc = 0; kc < 4; ++kc) {
            const float4 b4 = Xv[kc];
            const int k0 = 64 + kc * 4;
            ROW_FMA64(acc, b4.x, W_o + (size_t)(k0 + 0) * 64);
            ROW_FMA64(acc, b4.y, W_o + (size_t)(k0 + 1) * 64);
            ROW_FMA64(acc, b4.z, W_o + (size_t)(k0 + 2) * 64);
            ROW_FMA64(acc, b4.w, W_o + (size_t)(k0 + 3) * 64);
        }
    }
    {
        const float4* Ev = reinterpret_cast<const float4*>(E_hat + (size_t)n * 64);
#pragma unroll 2
        for (int kc = 0; kc < 16; ++kc) {
            const float4 b4 = Ev[kc];
            const int k0 = 80 + kc * 4;
            ROW_FMA64(acc, b4.x, W_o + (size_t)(k0 + 0) * 64);
            ROW_FMA64(acc, b4.y, W_o + (size_t)(k0 + 1) * 64);
            ROW_FMA64(acc, b4.z, W_o + (size_t)(k0 + 2) * 64);
            ROW_FMA64(acc, b4.w, W_o + (size_t)(k0 + 3) * 64);
        }
    }

    float sc[10];
#pragma unroll
    for (int c = 0; c < 10; ++c) sc[c] = b_s[c];
#pragma unroll 8
    for (int j = 0; j < 64; ++j) {
        const float* ws = W_s + (size_t)j * 10;
        const float p = acc[j];
#pragma unroll
        for (int c = 0; c < 10; ++c) sc[c] = fmaf(p, ws[c], sc[c]);
    }

    float m = sc[0];
#pragma unroll
    for (int c = 1; c < 10; ++c) m = fmaxf(m, sc[c]);
    float sum = 0.f;
#pragma unroll
    for (int c = 0; c < 10; ++c) {
        sc[c] = expf(sc[c] - m);
        sum += sc[c];
    }
    const float inv = 1.0f / sum;
    float* o = out + (size_t)n * 10;
#pragma unroll
    for (int c = 0; c < 10; ++c) o[c] = sc[c] * inv;
}

// ---------------------------------------------------------------------------
// Workspace layout (bytes) — non-overlapping, verified:
//   count  [0x0000000, 0x0030D40)   200000 B
//   off    [0x0040000, 0x0070D44)   200004 B
//   rank   [0x0080000, 0x038D400)   3.2 MB
//   perm   [0x0400000, 0x070D400)   3.2 MB
//   S_send [0x0800000, 0x1435000)   12.8 MB
//   S_ra   [0x1500000, 0x180D400)   3.2 MB   (prev round: overlapped degf!)
//   degf   [0x1900000, 0x1930D40)   200000 B
// ---------------------------------------------------------------------------
#define WS_COUNT   ((size_t)0x0000000)
#define WS_OFF     ((size_t)0x0040000)
#define WS_RANK    ((size_t)0x0080000)
#define WS_PERM    ((size_t)0x0400000)
#define WS_SSEND   ((size_t)0x0800000)
#define WS_SRA     ((size_t)0x1500000)
#define WS_DEGF    ((size_t)0x1900000)
#define WS_NEED    ((size_t)0x1930D40)

extern "C" void kernel_launch(void* const* d_in, const int* in_sizes, int n_in,
                              void* d_out, int out_size, void* d_ws, size_t ws_size,
                              hipStream_t stream)
{
    const float* O    = (const float*)d_in[0];
    const float* X    = (const float*)d_in[1];
    const float* R_a  = (const float*)d_in[2];
    const int* senders   = (const int*)d_in[3];
    const int* receivers = (const int*)d_in[4];
    const float* W_r  = (const float*)d_in[5];
    const float* b_r  = (const float*)d_in[6];
    const float* W_o  = (const float*)d_in[7];
    const float* b_o  = (const float*)d_in[8];
    const float* W_s  = (const float*)d_in[9];
    const float* b_s  = (const float*)d_in[10];
    float* out = (float*)d_out;
    char* ws = (char*)d_ws;

    if (ws_size < WS_NEED) {
        // Fallback: round-0 atomic path (needs only 12.8 MB)
        float* E_hat = (float*)ws;
        hipMemsetAsync(E_hat, 0, (size_t)N_NODES * 64 * sizeof(float), stream);
        in_edge_kernel<<<N_EDGES / 256, 256, 0, stream>>>(
            O, R_a, senders, receivers, W_r, b_r, E_hat);
        in_node_kernel<<<(N_NODES + 255) / 256, 256, 0, stream>>>(
            O, X, E_hat, W_o, b_o, W_s, b_s, out);
        return;
    }

    int* count = (int*)(ws + WS_COUNT);
    int* off   = (int*)(ws + WS_OFF);
    int* rank  = (int*)(ws + WS_RANK);
    int* perm  = (int*)(ws + WS_PERM);
    float* S_send = (float*)(ws + WS_SSEND);
    float* S_ra   = (float*)(ws + WS_SRA);
    float* degf   = (float*)(ws + WS_DEGF);

    hipMemsetAsync(count, 0, (size_t)N_NODES * sizeof(int), stream);

    count_rank_kernel<<<N_EDGES / 256, 256, 0, stream>>>(receivers, count, rank);
    scan_kernel<<<1, SCAN_BLOCK, 0, stream>>>(count, off);
    place_kernel<<<N_EDGES / 256, 256, 0, stream>>>(receivers, rank, off, perm);
    agg_kernel<<<(N_NODES + 3) / 4, 256, 0, stream>>>(
        O, R_a, senders, perm, off, S_send, S_ra, degf);
    fused_node_kernel<<<(N_NODES + 255) / 256, 256, 0, stream>>>(
        O, X, S_send, S_ra, degf, W_r, b_r, W_o, b_o, W_s, b_s, out);
}

// Round 4
// 259.933 us; speedup vs baseline: 11.2207x; 1.4759x over previous
//
#include <hip/hip_runtime.h>

#define N_NODES 50000
#define N_EDGES 800000
// D_S=64, D_R=16, D_E=64, D_X=16, D_P=64, NUM_CLASSES=10
// W_r: [144,64]; W_o: [144,64]; W_s: [64,10] (all row-major)
//
// Linear refactor: scores[n] = O[n]@A_O + X[n]@A_X + deg_n*(O[n]@A_dO + c0)
//                              + c1 + sum_{e->n} (O[s_e]@A_S + R_a[e]@A_R)
// with Wc = W_o@W_s [144,10], Wc2 = Wc[80:144],
//   A_O = Wc[0:64], A_X = Wc[64:80], A_S = W_r[0:64]@Wc2,
//   A_R = W_r[128:144]@Wc2, A_dO = W_r[64:128]@Wc2,
//   c0 = b_r@Wc2, c1 = b_o@W_s + b_s.
//
// A-table layout in ws: [226][16] f32 (cols 10..15 zeroed):
//   rows 0..63 A_O | 64..79 A_X | 80..143 A_S | 144..159 A_R |
//   160..223 A_dO | 224 c0 | 225 c1

// ---------------------------------------------------------------------------
// Workspace layout (bytes) — WS_NEED = 23,394,304 < 26,414,400 (proven in r3)
// ---------------------------------------------------------------------------
#define WS_A      ((size_t)0x000000)   // 226*16*4 = 14,464 B
#define WS_COUNT  ((size_t)0x010000)   // 50000 i32 = 200,000 B
#define WS_OFF    ((size_t)0x050000)   // 50001 i32 = 200,004 B
#define WS_CUR    ((size_t)0x090000)   // 50000 i32 = 200,000 B
#define WS_PERM   ((size_t)0x0D0000)   // 800000 i32 = 3,200,000 B
#define WS_W      ((size_t)0x400000)   // 800000*6 u32 (bf16 pairs) = 19,200,000 B

__device__ __forceinline__ unsigned int f32_to_bf16_rne(float f) {
    unsigned int x = __float_as_uint(f);
    return (x + 0x7fffu + ((x >> 16) & 1u)) >> 16;
}

// ---------------------------------------------------------------------------
// Precompute folded weight table A (single block)
// ---------------------------------------------------------------------------
__global__ __launch_bounds__(256) void precompute_A(
    const float* __restrict__ W_r, const float* __restrict__ b_r,
    const float* __restrict__ W_o, const float* __restrict__ b_o,
    const float* __restrict__ W_s, const float* __restrict__ b_s,
    float* __restrict__ A)
{
    __shared__ float Wc2[64 * 10];  // Wc rows 80..143
    const int t = threadIdx.x;

    // zero pad columns 10..15 of all 226 rows
    for (int idx = t; idx < 226 * 6; idx += 256) {
        const int row = idx / 6, c = 10 + idx % 6;
        A[row * 16 + c] = 0.f;
    }

    // phase 1: Wc[row][c] = sum_j W_o[row][j] * W_s[j][c]
    for (int idx = t; idx < 1440; idx += 256) {
        const int row = idx / 10, c = idx % 10;
        float acc = 0.f;
        for (int j = 0; j < 64; ++j)
            acc = fmaf(W_o[row * 64 + j], W_s[j * 10 + c], acc);
        if (row < 80) A[row * 16 + c] = acc;          // A_O / A_X
        else          Wc2[(row - 80) * 10 + c] = acc; // for phase 2
    }
    __syncthreads();

    // phase 2: A_S / A_R / A_dO / c0 / c1
    for (int idx = t; idx < 1460; idx += 256) {
        const int c = (idx < 1440) ? (idx % 10)
                    : (idx < 1450) ? (idx - 1440) : (idx - 1450);
        float acc = 0.f;
        int arow;
        if (idx < 640) {                       // A_S: W_r rows 0..63
            const int k = idx / 10; arow = 80 + k;
            const float* src = W_r + (size_t)k * 64;
            for (int m = 0; m < 64; ++m) acc = fmaf(src[m], Wc2[m * 10 + c], acc);
        } else if (idx < 800) {                // A_R: W_r rows 128..143
            const int k = (idx - 640) / 10; arow = 144 + k;
            const float* src = W_r + (size_t)(128 + k) * 64;
            for (int m = 0; m < 64; ++m) acc = fmaf(src[m], Wc2[m * 10 + c], acc);
        } else if (idx < 1440) {               // A_dO: W_r rows 64..127
            const int k = (idx - 800) / 10; arow = 160 + k;
            const float* src = W_r + (size_t)(64 + k) * 64;
            for (int m = 0; m < 64; ++m) acc = fmaf(src[m], Wc2[m * 10 + c], acc);
        } else if (idx < 1450) {               // c0 = b_r @ Wc2
            arow = 224;
            for (int m = 0; m < 64; ++m) acc = fmaf(b_r[m], Wc2[m * 10 + c], acc);
        } else {                               // c1 = b_o @ W_s + b_s
            arow = 225;
            acc = b_s[c];
            for (int j = 0; j < 64; ++j) acc = fmaf(b_o[j], W_s[j * 10 + c], acc);
        }
        A[arow * 16 + c] = acc;
    }
}

// ---------------------------------------------------------------------------
// Per-edge 10-vector w_e = O[s_e]@A_S + R_a[e]@A_R (bf16-packed),
// plus receiver histogram (atomic int).
// ---------------------------------------------------------------------------
__global__ __launch_bounds__(256) void edge_w_kernel(
    const float* __restrict__ O, const float* __restrict__ R_a,
    const int* __restrict__ senders, const int* __restrict__ receivers,
    const float* __restrict__ A,
    unsigned int* __restrict__ wout,   // [E][6] dwords, 24 B stride
    int* __restrict__ count)
{
    const int e = blockIdx.x * blockDim.x + threadIdx.x;
    if (e >= N_EDGES) return;
    const int s = senders[e];

    float a[10];
#pragma unroll
    for (int c = 0; c < 10; ++c) a[c] = 0.f;

    // O[s] @ A_S (A rows 80..143)
    const float4* Ov = reinterpret_cast<const float4*>(O + (size_t)s * 64);
#pragma unroll 4
    for (int kc = 0; kc < 16; ++kc) {
        const float4 b4 = Ov[kc];
        const float* A0 = A + (size_t)(80 + kc * 4) * 16;
#pragma unroll
        for (int c = 0; c < 10; ++c) a[c] = fmaf(b4.x, A0[c], a[c]);
#pragma unroll
        for (int c = 0; c < 10; ++c) a[c] = fmaf(b4.y, A0[16 + c], a[c]);
#pragma unroll
        for (int c = 0; c < 10; ++c) a[c] = fmaf(b4.z, A0[32 + c], a[c]);
#pragma unroll
        for (int c = 0; c < 10; ++c) a[c] = fmaf(b4.w, A0[48 + c], a[c]);
    }
    // R_a[e] @ A_R (A rows 144..159)
    const float4* Rv = reinterpret_cast<const float4*>(R_a + (size_t)e * 16);
#pragma unroll
    for (int kc = 0; kc < 4; ++kc) {
        const float4 b4 = Rv[kc];
        const float* A0 = A + (size_t)(144 + kc * 4) * 16;
#pragma unroll
        for (int c = 0; c < 10; ++c) a[c] = fmaf(b4.x, A0[c], a[c]);
#pragma unroll
        for (int c = 0; c < 10; ++c) a[c] = fmaf(b4.y, A0[16 + c], a[c]);
#pragma unroll
        for (int c = 0; c < 10; ++c) a[c] = fmaf(b4.z, A0[32 + c], a[c]);
#pragma unroll
        for (int c = 0; c < 10; ++c) a[c] = fmaf(b4.w, A0[48 + c], a[c]);
    }

    // pack 10 f32 -> 5 dwords of bf16 pairs
    unsigned int* wp = wout + (size_t)e * 6;
#pragma unroll
    for (int q = 0; q < 5; ++q) {
        const unsigned int u = f32_to_bf16_rne(a[2 * q]) |
                               (f32_to_bf16_rne(a[2 * q + 1]) << 16);
        wp[q] = u;
    }

    atomicAdd(count + receivers[e], 1);
}

// ---------------------------------------------------------------------------
// Exclusive scan of count -> off (and cursor copy), single block
// ---------------------------------------------------------------------------
#define SCAN_BLOCK 1024
#define SCAN_CHUNK 49  // 1024*49 = 50176 >= 50000

__global__ __launch_bounds__(SCAN_BLOCK) void scan_kernel(
    const int* __restrict__ count,
    int* __restrict__ off, int* __restrict__ cur)
{
    __shared__ int tmp[SCAN_BLOCK];
    const int t = threadIdx.x;
    const int base = t * SCAN_CHUNK;
    int loc[SCAN_CHUNK];
    int s = 0;
#pragma unroll
    for (int i = 0; i < SCAN_CHUNK; ++i) {
        const int idx = base + i;
        loc[i] = (idx < N_NODES) ? count[idx] : 0;
        s += loc[i];
    }
    tmp[t] = s;
    __syncthreads();
    for (int d = 1; d < SCAN_BLOCK; d <<= 1) {
        int v = (t >= d) ? tmp[t - d] : 0;
        __syncthreads();
        tmp[t] += v;
        __syncthreads();
    }
    int run = tmp[t] - s;
#pragma unroll
    for (int i = 0; i < SCAN_CHUNK; ++i) {
        const int idx = base + i;
        if (idx < N_NODES) {
            off[idx] = run;
            cur[idx] = run;
            run += loc[i];
        }
    }
    if (t == SCAN_BLOCK - 1) off[N_NODES] = tmp[SCAN_BLOCK - 1];
}

// ---------------------------------------------------------------------------
// Scatter edge ids into receiver-sorted order (rank merged via cursor atomic)
// ---------------------------------------------------------------------------
__global__ __launch_bounds__(256) void place_kernel(
    const int* __restrict__ receivers,
    int* __restrict__ cur, int* __restrict__ perm)
{
    const int e = blockIdx.x * blockDim.x + threadIdx.x;
    if (e >= N_EDGES) return;
    const int r = receivers[e];
    const int pos = atomicAdd(cur + r, 1);
    perm[pos] = e;
}

// ---------------------------------------------------------------------------
// Node scores: thread = (node, class-slot c<16); gathers bf16 w_e, softmax.
// ---------------------------------------------------------------------------
__global__ __launch_bounds__(256) void node_score_kernel(
    const float* __restrict__ O, const float* __restrict__ X,
    const int* __restrict__ off, const int* __restrict__ perm,
    const unsigned int* __restrict__ w,   // [E][6] dwords
    const float* __restrict__ A,
    float* __restrict__ out)
{
    const int tid = blockIdx.x * 256 + threadIdx.x;
    const int n = tid >> 4;
    const int c = tid & 15;
    if (n >= N_NODES) return;

    float s1 = 0.f, s2 = 0.f;
    // O part: A_O (rows 0..63) and A_dO (rows 160..223)
#pragma unroll 8
    for (int k = 0; k < 64; ++k) {
        const float o = O[(size_t)n * 64 + k];
        s1 = fmaf(o, A[(size_t)k * 16 + c], s1);
        s2 = fmaf(o, A[(size_t)(160 + k) * 16 + c], s2);
    }
    // X part: A_X (rows 64..79)
#pragma unroll
    for (int k = 0; k < 16; ++k) {
        const float x = X[(size_t)n * 16 + k];
        s1 = fmaf(x, A[(size_t)(64 + k) * 16 + c], s1);
    }

    const int beg = off[n];
    const int end = off[n + 1];
    const float dg = (float)(end - beg);
    float sc = s1 + dg * s2 + dg * A[224 * 16 + c] + A[225 * 16 + c];

    // gather-sum bf16 w_e over incoming edges
    const int half = (c < 10) ? (c >> 1) : 0;
    const int sh = (c & 1) * 16;
    int i = beg;
    for (; i + 3 < end; i += 4) {
        const int p0 = perm[i], p1 = perm[i + 1], p2 = perm[i + 2], p3 = perm[i + 3];
        const unsigned int u0 = w[(size_t)p0 * 6 + half];
        const unsigned int u1 = w[(size_t)p1 * 6 + half];
        const unsigned int u2 = w[(size_t)p2 * 6 + half];
        const unsigned int u3 = w[(size_t)p3 * 6 + half];
        sc += __uint_as_float((u0 >> sh) << 16);
        sc += __uint_as_float((u1 >> sh) << 16);
        sc += __uint_as_float((u2 >> sh) << 16);
        sc += __uint_as_float((u3 >> sh) << 16);
    }
    for (; i < end; ++i) {
        const int p = perm[i];
        const unsigned int u = w[(size_t)p * 6 + half];
        sc += __uint_as_float((u >> sh) << 16);
    }

    // softmax over the 10 active lanes of this 16-lane group
    float m = (c < 10) ? sc : -3.0e38f;
#pragma unroll
    for (int d = 1; d < 16; d <<= 1) m = fmaxf(m, __shfl_xor(m, d, 16));
    const float ex = (c < 10) ? __expf(sc - m) : 0.f;
    float sum = ex;
#pragma unroll
    for (int d = 1; d < 16; d <<= 1) sum += __shfl_xor(sum, d, 16);
    if (c < 10) out[(size_t)n * 10 + c] = ex / sum;
}

extern "C" void kernel_launch(void* const* d_in, const int* in_sizes, int n_in,
                              void* d_out, int out_size, void* d_ws, size_t ws_size,
                              hipStream_t stream)
{
    const float* O    = (const float*)d_in[0];
    const float* X    = (const float*)d_in[1];
    const float* R_a  = (const float*)d_in[2];
    const int* senders   = (const int*)d_in[3];
    const int* receivers = (const int*)d_in[4];
    const float* W_r  = (const float*)d_in[5];
    const float* b_r  = (const float*)d_in[6];
    const float* W_o  = (const float*)d_in[7];
    const float* b_o  = (const float*)d_in[8];
    const float* W_s  = (const float*)d_in[9];
    const float* b_s  = (const float*)d_in[10];
    float* out = (float*)d_out;
    char* ws = (char*)d_ws;

    float* A    = (float*)(ws + WS_A);
    int* count  = (int*)(ws + WS_COUNT);
    int* off    = (int*)(ws + WS_OFF);
    int* cur    = (int*)(ws + WS_CUR);
    int* perm   = (int*)(ws + WS_PERM);
    unsigned int* w = (unsigned int*)(ws + WS_W);

    hipMemsetAsync(count, 0, (size_t)N_NODES * sizeof(int), stream);

    precompute_A<<<1, 256, 0, stream>>>(W_r, b_r, W_o, b_o, W_s, b_s, A);

    edge_w_kernel<<<(N_EDGES + 255) / 256, 256, 0, stream>>>(
        O, R_a, senders, receivers, A, w, count);

    scan_kernel<<<1, SCAN_BLOCK, 0, stream>>>(count, off, cur);

    place_kernel<<<(N_EDGES + 255) / 256, 256, 0, stream>>>(receivers, cur, perm);

    node_score_kernel<<<(N_NODES * 16 + 255) / 256, 256, 0, stream>>>(
        O, X, off, perm, w, A, out);
}

// Round 5
// 179.171 us; speedup vs baseline: 16.2784x; 1.4508x over previous
//
#include <hip/hip_runtime.h>

#define N_NODES 50000
#define N_EDGES 800000
// D_S=64, D_R=16, D_E=64, D_X=16, D_P=64, NUM_CLASSES=10
// W_r: [144,64]; W_o: [144,64]; W_s: [64,10] (all row-major)
//
// Linear refactor: scores[n] = O[n]@A_O + X[n]@A_X + deg_n*(O[n]@A_dO + c0)
//                              + c1 + sum_{e->n} (O[s_e]@A_S + R_a[e]@A_R)
// with Wc = W_o@W_s [144,10], Wc2 = Wc[80:144],
//   A_O = Wc[0:64], A_X = Wc[64:80], A_S = W_r[0:64]@Wc2,
//   A_R = W_r[128:144]@Wc2, A_dO = W_r[64:128]@Wc2,
//   c0 = b_r@Wc2, c1 = b_o@W_s + b_s.
//
// A-table layout in ws: [226][16] f32 (cols 10..15 zeroed):
//   rows 0..63 A_O | 64..79 A_X | 80..143 A_S | 144..159 A_R |
//   160..223 A_dO | 224 c0 | 225 c1
//
// CSR trick: segment offsets need NOT be ordered prefix sums — disjoint
// contiguous segments suffice. off[n] = atomicAdd(cursor, count[n]) replaces
// the 80 us single-block scan; edges then self-place into sorted slots
// inside edge_w (fusing the old place_kernel away).

// ---------------------------------------------------------------------------
// Workspace layout (bytes) — WS_NEED = 0x0D0000 + 19,200,000 = 20.1 MB
// ---------------------------------------------------------------------------
#define WS_A       ((size_t)0x000000)   // 226*16*4 = 14,464 B
#define WS_COUNT   ((size_t)0x010000)   // 50000 i32 = 200,000 B
#define WS_CURSOR  (WS_COUNT + (size_t)200000)  // 1 u32 (memset with count)
#define WS_OFF     ((size_t)0x050000)   // 50000 i32
#define WS_CUR     ((size_t)0x090000)   // 50000 i32
#define WS_W       ((size_t)0x0D0000)   // 800000*6 u32 (bf16 pairs) = 19.2 MB

__device__ __forceinline__ unsigned int f32_to_bf16_rne(float f) {
    unsigned int x = __float_as_uint(f);
    return (x + 0x7fffu + ((x >> 16) & 1u)) >> 16;
}

// ---------------------------------------------------------------------------
// Precompute folded weight table A (single block, 1024 threads)
// ---------------------------------------------------------------------------
__global__ __launch_bounds__(1024) void precompute_A(
    const float* __restrict__ W_r, const float* __restrict__ b_r,
    const float* __restrict__ W_o, const float* __restrict__ b_o,
    const float* __restrict__ W_s, const float* __restrict__ b_s,
    float* __restrict__ A)
{
    __shared__ float Wc2[64 * 10];  // Wc rows 80..143
    const int t = threadIdx.x;
    const int nt = blockDim.x;

    // zero pad columns 10..15 of all 226 rows
    for (int idx = t; idx < 226 * 6; idx += nt) {
        const int row = idx / 6, c = 10 + idx % 6;
        A[row * 16 + c] = 0.f;
    }

    // phase 1: Wc[row][c] = sum_j W_o[row][j] * W_s[j][c]
    for (int idx = t; idx < 1440; idx += nt) {
        const int row = idx / 10, c = idx % 10;
        float acc = 0.f;
        for (int j = 0; j < 64; ++j)
            acc = fmaf(W_o[row * 64 + j], W_s[j * 10 + c], acc);
        if (row < 80) A[row * 16 + c] = acc;          // A_O / A_X
        else          Wc2[(row - 80) * 10 + c] = acc; // for phase 2
    }
    __syncthreads();

    // phase 2: A_S / A_R / A_dO / c0 / c1
    for (int idx = t; idx < 1460; idx += nt) {
        const int c = (idx < 1440) ? (idx % 10)
                    : (idx < 1450) ? (idx - 1440) : (idx - 1450);
        float acc = 0.f;
        int arow;
        if (idx < 640) {                       // A_S: W_r rows 0..63
            const int k = idx / 10; arow = 80 + k;
            const float* src = W_r + (size_t)k * 64;
            for (int m = 0; m < 64; ++m) acc = fmaf(src[m], Wc2[m * 10 + c], acc);
        } else if (idx < 800) {                // A_R: W_r rows 128..143
            const int k = (idx - 640) / 10; arow = 144 + k;
            const float* src = W_r + (size_t)(128 + k) * 64;
            for (int m = 0; m < 64; ++m) acc = fmaf(src[m], Wc2[m * 10 + c], acc);
        } else if (idx < 1440) {               // A_dO: W_r rows 64..127
            const int k = (idx - 800) / 10; arow = 160 + k;
            const float* src = W_r + (size_t)(64 + k) * 64;
            for (int m = 0; m < 64; ++m) acc = fmaf(src[m], Wc2[m * 10 + c], acc);
        } else if (idx < 1450) {               // c0 = b_r @ Wc2
            arow = 224;
            for (int m = 0; m < 64; ++m) acc = fmaf(b_r[m], Wc2[m * 10 + c], acc);
        } else {                               // c1 = b_o @ W_s + b_s
            arow = 225;
            acc = b_s[c];
            for (int j = 0; j < 64; ++j) acc = fmaf(b_o[j], W_s[j * 10 + c], acc);
        }
        A[arow * 16 + c] = acc;
    }
}

// ---------------------------------------------------------------------------
// Receiver histogram, 4 edges/thread (int4 loads)
// ---------------------------------------------------------------------------
__global__ __launch_bounds__(256) void count_kernel(
    const int* __restrict__ receivers, int* __restrict__ count)
{
    const int t = blockIdx.x * 256 + threadIdx.x;
    if (t * 4 >= N_EDGES) return;
    const int4 r4 = reinterpret_cast<const int4*>(receivers)[t];
    atomicAdd(count + r4.x, 1);
    atomicAdd(count + r4.y, 1);
    atomicAdd(count + r4.z, 1);
    atomicAdd(count + r4.w, 1);
}

// ---------------------------------------------------------------------------
// Segment allocation: off[n] = atomicAdd(cursor, count[n]) (order-free CSR)
// ---------------------------------------------------------------------------
__global__ __launch_bounds__(256) void alloc_kernel(
    const int* __restrict__ count, unsigned int* __restrict__ cursor,
    int* __restrict__ off, int* __restrict__ cur)
{
    const int n = blockIdx.x * 256 + threadIdx.x;
    if (n >= N_NODES) return;
    const int c = count[n];
    const int pos = (int)atomicAdd(cursor, (unsigned int)c);
    off[n] = pos;
    cur[n] = pos;
}

// ---------------------------------------------------------------------------
// Per-edge 10-vector w_e = O[s_e]@A_S + R_a[e]@A_R, bf16-packed, written
// DIRECTLY into its receiver-sorted slot (place fused via cursor atomic).
// ---------------------------------------------------------------------------
__global__ __launch_bounds__(256) void edge_w_kernel(
    const float* __restrict__ O, const float* __restrict__ R_a,
    const int* __restrict__ senders, const int* __restrict__ receivers,
    const float* __restrict__ A,
    int* __restrict__ cur,
    unsigned int* __restrict__ wsorted)   // [E][6] dwords, 24 B stride
{
    const int e = blockIdx.x * blockDim.x + threadIdx.x;
    if (e >= N_EDGES) return;
    const int s = senders[e];

    float a[10];
#pragma unroll
    for (int c = 0; c < 10; ++c) a[c] = 0.f;

    // O[s] @ A_S (A rows 80..143)
    const float4* Ov = reinterpret_cast<const float4*>(O + (size_t)s * 64);
#pragma unroll 4
    for (int kc = 0; kc < 16; ++kc) {
        const float4 b4 = Ov[kc];
        const float* A0 = A + (size_t)(80 + kc * 4) * 16;
#pragma unroll
        for (int c = 0; c < 10; ++c) a[c] = fmaf(b4.x, A0[c], a[c]);
#pragma unroll
        for (int c = 0; c < 10; ++c) a[c] = fmaf(b4.y, A0[16 + c], a[c]);
#pragma unroll
        for (int c = 0; c < 10; ++c) a[c] = fmaf(b4.z, A0[32 + c], a[c]);
#pragma unroll
        for (int c = 0; c < 10; ++c) a[c] = fmaf(b4.w, A0[48 + c], a[c]);
    }
    // R_a[e] @ A_R (A rows 144..159)
    const float4* Rv = reinterpret_cast<const float4*>(R_a + (size_t)e * 16);
#pragma unroll
    for (int kc = 0; kc < 4; ++kc) {
        const float4 b4 = Rv[kc];
        const float* A0 = A + (size_t)(144 + kc * 4) * 16;
#pragma unroll
        for (int c = 0; c < 10; ++c) a[c] = fmaf(b4.x, A0[c], a[c]);
#pragma unroll
        for (int c = 0; c < 10; ++c) a[c] = fmaf(b4.y, A0[16 + c], a[c]);
#pragma unroll
        for (int c = 0; c < 10; ++c) a[c] = fmaf(b4.z, A0[32 + c], a[c]);
#pragma unroll
        for (int c = 0; c < 10; ++c) a[c] = fmaf(b4.w, A0[48 + c], a[c]);
    }

    // claim sorted slot & write bf16-packed w (5 dwords, 24 B stride -> 8-aligned)
    const int r = receivers[e];
    const int pos = atomicAdd(cur + r, 1);
    unsigned int* wp = wsorted + (size_t)pos * 6;
    uint2 u01, u23;
    u01.x = f32_to_bf16_rne(a[0]) | (f32_to_bf16_rne(a[1]) << 16);
    u01.y = f32_to_bf16_rne(a[2]) | (f32_to_bf16_rne(a[3]) << 16);
    u23.x = f32_to_bf16_rne(a[4]) | (f32_to_bf16_rne(a[5]) << 16);
    u23.y = f32_to_bf16_rne(a[6]) | (f32_to_bf16_rne(a[7]) << 16);
    *reinterpret_cast<uint2*>(wp) = u01;
    *reinterpret_cast<uint2*>(wp + 2) = u23;
    wp[4] = f32_to_bf16_rne(a[8]) | (f32_to_bf16_rne(a[9]) << 16);
}

// ---------------------------------------------------------------------------
// Node scores: thread = (node, class-slot c<16); contiguous w gather; softmax.
// ---------------------------------------------------------------------------
__global__ __launch_bounds__(256) void node_score_kernel(
    const float* __restrict__ O, const float* __restrict__ X,
    const int* __restrict__ off, const int* __restrict__ count,
    const unsigned int* __restrict__ w,   // [E][6] dwords, receiver-sorted
    const float* __restrict__ A,
    float* __restrict__ out)
{
    const int tid = blockIdx.x * 256 + threadIdx.x;
    const int n = tid >> 4;
    const int c = tid & 15;
    if (n >= N_NODES) return;

    float s1 = 0.f, s2 = 0.f;
    // O part: A_O (rows 0..63) and A_dO (rows 160..223)
#pragma unroll 8
    for (int k = 0; k < 64; ++k) {
        const float o = O[(size_t)n * 64 + k];
        s1 = fmaf(o, A[(size_t)k * 16 + c], s1);
        s2 = fmaf(o, A[(size_t)(160 + k) * 16 + c], s2);
    }
    // X part: A_X (rows 64..79)
#pragma unroll
    for (int k = 0; k < 16; ++k) {
        const float x = X[(size_t)n * 16 + k];
        s1 = fmaf(x, A[(size_t)(64 + k) * 16 + c], s1);
    }

    const int beg = off[n];
    const int dge = count[n];
    const int end = beg + dge;
    const float dg = (float)dge;
    float sc = s1 + dg * s2 + dg * A[224 * 16 + c] + A[225 * 16 + c];

    // sum bf16 w_e over this node's contiguous segment
    const int half = (c < 10) ? (c >> 1) : 0;
    const int sh = (c & 1) * 16;
    int i = beg;
    for (; i + 3 < end; i += 4) {
        const unsigned int u0 = w[(size_t)(i + 0) * 6 + half];
        const unsigned int u1 = w[(size_t)(i + 1) * 6 + half];
        const unsigned int u2 = w[(size_t)(i + 2) * 6 + half];
        const unsigned int u3 = w[(size_t)(i + 3) * 6 + half];
        sc += __uint_as_float((u0 >> sh) << 16);
        sc += __uint_as_float((u1 >> sh) << 16);
        sc += __uint_as_float((u2 >> sh) << 16);
        sc += __uint_as_float((u3 >> sh) << 16);
    }
    for (; i < end; ++i) {
        const unsigned int u = w[(size_t)i * 6 + half];
        sc += __uint_as_float((u >> sh) << 16);
    }

    // softmax over the 10 active lanes of this 16-lane group
    float m = (c < 10) ? sc : -3.0e38f;
#pragma unroll
    for (int d = 1; d < 16; d <<= 1) m = fmaxf(m, __shfl_xor(m, d, 16));
    const float ex = (c < 10) ? __expf(sc - m) : 0.f;
    float sum = ex;
#pragma unroll
    for (int d = 1; d < 16; d <<= 1) sum += __shfl_xor(sum, d, 16);
    if (c < 10) out[(size_t)n * 10 + c] = ex / sum;
}

extern "C" void kernel_launch(void* const* d_in, const int* in_sizes, int n_in,
                              void* d_out, int out_size, void* d_ws, size_t ws_size,
                              hipStream_t stream)
{
    const float* O    = (const float*)d_in[0];
    const float* X    = (const float*)d_in[1];
    const float* R_a  = (const float*)d_in[2];
    const int* senders   = (const int*)d_in[3];
    const int* receivers = (const int*)d_in[4];
    const float* W_r  = (const float*)d_in[5];
    const float* b_r  = (const float*)d_in[6];
    const float* W_o  = (const float*)d_in[7];
    const float* b_o  = (const float*)d_in[8];
    const float* W_s  = (const float*)d_in[9];
    const float* b_s  = (const float*)d_in[10];
    float* out = (float*)d_out;
    char* ws = (char*)d_ws;

    float* A      = (float*)(ws + WS_A);
    int* count    = (int*)(ws + WS_COUNT);
    unsigned int* cursor = (unsigned int*)(ws + WS_CURSOR);
    int* off      = (int*)(ws + WS_OFF);
    int* cur      = (int*)(ws + WS_CUR);
    unsigned int* w = (unsigned int*)(ws + WS_W);

    // zero count histogram + cursor (adjacent) in one memset
    hipMemsetAsync(count, 0, (size_t)200004, stream);

    precompute_A<<<1, 1024, 0, stream>>>(W_r, b_r, W_o, b_o, W_s, b_s, A);

    count_kernel<<<(N_EDGES / 4 + 255) / 256, 256, 0, stream>>>(receivers, count);

    alloc_kernel<<<(N_NODES + 255) / 256, 256, 0, stream>>>(count, cursor, off, cur);

    edge_w_kernel<<<(N_EDGES + 255) / 256, 256, 0, stream>>>(
        O, R_a, senders, receivers, A, cur, w);

    node_score_kernel<<<(N_NODES * 16 + 255) / 256, 256, 0, stream>>>(
        O, X, off, count, w, A, out);
}